// Round 3
// 517.892 us; speedup vs baseline: 1.0247x; 1.0247x over previous
//
#include <hip/hip_runtime.h>
#include <math.h>

#define BB 16
#define CC 256
#define HWSZ 16384   // 128*128
#define CRED 16
#define K3 48        // 3 * C/r

typedef float vfloat4 __attribute__((ext_vector_type(4)));   // clang vector: valid for nontemporal builtins

__device__ __forceinline__ float sigmoidf_(float v) { return 1.0f / (1.0f + expf(-v)); }

// ---------------- Kernel 1: per-(b,c) global avg + max pool ----------------
// Default (caching) loads on purpose: x is exactly 256 MiB == L3 capacity,
// we want it resident for the scale pass.
__global__ __launch_bounds__(256) void pool_kernel(const float* __restrict__ x,
                                                   float* __restrict__ avg,
                                                   float* __restrict__ mx) {
    const int bid = blockIdx.x;                  // b*C + c, 0..4095
    const int tid = threadIdx.x;
    const vfloat4* __restrict__ xp = (const vfloat4*)(x + (size_t)bid * HWSZ);

    float s = 0.0f;
    float m = -INFINITY;
#pragma unroll
    for (int i = 0; i < 16; ++i) {
        vfloat4 v = xp[tid + i * 256];
        s += (v.x + v.y) + (v.z + v.w);
        m = fmaxf(m, fmaxf(fmaxf(v.x, v.y), fmaxf(v.z, v.w)));
    }
    // wave-64 butterfly reduce
#pragma unroll
    for (int off = 32; off > 0; off >>= 1) {
        s += __shfl_down(s, off, 64);
        m = fmaxf(m, __shfl_down(m, off, 64));
    }
    __shared__ float ss[4], sm[4];
    const int wave = tid >> 6;
    const int lane = tid & 63;
    if (lane == 0) { ss[wave] = s; sm[wave] = m; }
    __syncthreads();
    if (tid == 0) {
        float ts = (ss[0] + ss[1]) + (ss[2] + ss[3]);
        float tm = fmaxf(fmaxf(sm[0], sm[1]), fmaxf(sm[2], sm[3]));
        __builtin_nontemporal_store(ts * (1.0f / (float)HWSZ), &avg[bid]);
        __builtin_nontemporal_store(tm, &mx[bid]);
    }
}

// ---------------- Kernel 2: squeeze-excite MLP -> gate ----------------
// grid = 16 (one block per batch sample), block = 256 (one thread per out chan)
__global__ __launch_bounds__(256) void gate_kernel(
    const float* __restrict__ avg, const float* __restrict__ mx,
    const float* __restrict__ w1, const float* __restrict__ b1,
    const float* __restrict__ w2, const float* __restrict__ b2,
    const float* __restrict__ w3, const float* __restrict__ b3,
    const float* __restrict__ w4, const float* __restrict__ b4,
    float* __restrict__ gate) {
    const int b = blockIdx.x;
    const int tid = threadIdx.x;

    __shared__ float h[2][K3];   // hidden activations for avg-branch and max-branch

    if (tid < 2 * K3) {
        const int br = tid / K3;          // 0 = avg branch, 1 = max branch
        const int k  = tid % K3;
        const float* __restrict__ p = (br == 0 ? avg : mx) + b * CC;
        const float* wsrc; const float* bsrc; int j;
        if (k < CRED)          { wsrc = w1; bsrc = b1; j = k; }
        else if (k < 2 * CRED) { wsrc = w2; bsrc = b2; j = k - CRED; }
        else                   { wsrc = w3; bsrc = b3; j = k - 2 * CRED; }
        // center tap of 3x3: index j*C*9 + c*9 + 4
        const float* __restrict__ wrow = wsrc + (size_t)j * (CC * 9) + 4;
        float acc = bsrc[j];
        for (int c = 0; c < CC; ++c) acc += p[c] * wrow[c * 9];
        h[br][k] = fmaxf(acc, 0.0f);
    }
    __syncthreads();

    const int o = tid;   // output channel
    const float* __restrict__ w4row = w4 + (size_t)o * (K3 * 9) + 4;
    float la = b4[o];
    float lm = la;
#pragma unroll
    for (int k = 0; k < K3; ++k) {
        float wv = w4row[k * 9];
        la += h[0][k] * wv;
        lm += h[1][k] * wv;
    }
    float g = sigmoidf_(sigmoidf_(la) + sigmoidf_(lm));
    __builtin_nontemporal_store(g, &gate[b * CC + o]);
}

// ---------------- Kernel 3: scale x by gate ----------------
// Reads of x: default caching (expect L3 hits — x was just streamed by pool).
// Stores of out: NONTEMPORAL so the 256 MiB write stream does not evict x
// from the 256 MiB Infinity Cache.
__global__ __launch_bounds__(256) void scale_kernel(const float* __restrict__ x,
                                                    const float* __restrict__ gate,
                                                    float* __restrict__ out) {
    const int bid = blockIdx.x;                  // b*C + c
    const int tid = threadIdx.x;
    const float g = gate[bid];
    const vfloat4* __restrict__ xp = (const vfloat4*)(x + (size_t)bid * HWSZ);
    vfloat4* __restrict__ op = (vfloat4*)(out + (size_t)bid * HWSZ);
#pragma unroll
    for (int i = 0; i < 16; ++i) {
        vfloat4 v = xp[tid + i * 256];
        v *= g;
        __builtin_nontemporal_store(v, &op[tid + i * 256]);
    }
}

extern "C" void kernel_launch(void* const* d_in, const int* in_sizes, int n_in,
                              void* d_out, int out_size, void* d_ws, size_t ws_size,
                              hipStream_t stream) {
    const float* x  = (const float*)d_in[0];
    const float* w1 = (const float*)d_in[1];
    const float* b1 = (const float*)d_in[2];
    const float* w2 = (const float*)d_in[3];
    const float* b2 = (const float*)d_in[4];
    const float* w3 = (const float*)d_in[5];
    const float* b3 = (const float*)d_in[6];
    const float* w4 = (const float*)d_in[7];
    const float* b4 = (const float*)d_in[8];
    float* out = (float*)d_out;

    float* avg  = (float*)d_ws;          // 4096 floats
    float* mx   = avg + BB * CC;         // 4096 floats
    float* gate = mx + BB * CC;          // 4096 floats

    pool_kernel<<<BB * CC, 256, 0, stream>>>(x, avg, mx);
    gate_kernel<<<BB, 256, 0, stream>>>(avg, mx, w1, b1, w2, b2, w3, b3, w4, b4, gate);
    scale_kernel<<<BB * CC, 256, 0, stream>>>(x, gate, out);
}